// Round 2
// baseline (522.643 us; speedup 1.0000x reference)
//
#include <hip/hip_runtime.h>

// ---------------------------------------------------------------------------
// DifferentiableTreeDense: out[b, l*128+o] =
//    leaf_prob[b,l] * (dot(x[b,:], leaf_w[l,:,o]) + bias[l,o])
// leaf_prob[b,l] = prod_d sigmoid(logit[b,node_d,dir_d] - logit[b,node_d,!dir_d])
//
// bf16 MFMA GEMMs (32x32x16), XOR-swizzled LDS staging, fused leaf-prob.
// ---------------------------------------------------------------------------

typedef __attribute__((ext_vector_type(8)))  short short8;
typedef __attribute__((ext_vector_type(4)))  float f32x4;
typedef __attribute__((ext_vector_type(16))) float f32x16;

#define BATCH 8192
#define FEAT  1024
#define NLEAF 64
#define LEAFD 128
#define OUTD  8192

__device__ __forceinline__ unsigned short f2bf(float f) {
    union { float f; unsigned int u; } c; c.f = f;
    unsigned int u = c.u;
    return (unsigned short)((u + 0x7FFFu + ((u >> 16) & 1u)) >> 16);  // RNE
}

__device__ __forceinline__ void gload16(const void* g, void* l) {
    __builtin_amdgcn_global_load_lds(
        (const __attribute__((address_space(1))) unsigned int*)g,
        (__attribute__((address_space(3))) unsigned int*)l, 16, 0, 0);
}

// --------------------------- conversion kernels ----------------------------

// x fp32 [8192][1024] -> bf16 same layout
__global__ __launch_bounds__(256) void cvt_x(const float* __restrict__ x,
                                             unsigned short* __restrict__ xb) {
    const int i = (blockIdx.x * 256 + threadIdx.x) * 4;
    const float4 v = *(const float4*)(x + i);
    ushort4 o;
    o.x = f2bf(v.x); o.y = f2bf(v.y); o.z = f2bf(v.z); o.w = f2bf(v.w);
    *(ushort4*)(xb + i) = o;
}

// leaf_weights fp32 [64][1024][128] -> bf16 transposed [64][128][1024]
// 64(k) x 32(o) tile; float4 loads, ushort8 (16B) stores.
__global__ __launch_bounds__(256) void cvt_lw(const float* __restrict__ lw,
                                              unsigned short* __restrict__ wt) {
    __shared__ float tile[64][33];
    const int l  = blockIdx.x;
    const int k0 = blockIdx.y * 64;
    const int o0 = blockIdx.z * 32;
    const int t  = threadIdx.x;
    const float* src = lw + (size_t)l * (FEAT * LEAFD) + (size_t)k0 * LEAFD + o0;
    {
        const int fc = (t & 7) * 4;
        const int r  = t >> 3;               // 0..31
#pragma unroll
        for (int p = 0; p < 2; ++p) {
            const float4 v = *(const float4*)(src + (size_t)(r + p * 32) * LEAFD + fc);
            tile[r + p * 32][fc]     = v.x;
            tile[r + p * 32][fc + 1] = v.y;
            tile[r + p * 32][fc + 2] = v.z;
            tile[r + p * 32][fc + 3] = v.w;
        }
    }
    __syncthreads();
    const int o  = t >> 3;                   // 0..31
    const int kg = (t & 7) * 8;              // 0..56
    short8 u;
#pragma unroll
    for (int j = 0; j < 8; ++j) u[j] = (short)f2bf(tile[kg + j][o]);
    *(short8*)(wt + (size_t)l * (LEAFD * FEAT) + (size_t)(o0 + o) * FEAT + k0 + kg) = u;
}

// routing_weights fp32 [63][1024][2] -> bf16 [128][1024], row = n*2+d, rows 126/127 = 0
__global__ __launch_bounds__(256) void cvt_rw(const float* __restrict__ rw,
                                              unsigned short* __restrict__ rt) {
    const int gid = blockIdx.x * 256 + threadIdx.x;
    const int row = gid >> 10;
    const int f   = gid & 1023;
    const float v = (row < 126) ? rw[(size_t)(row >> 1) * 2048 + f * 2 + (row & 1)] : 0.0f;
    rt[gid] = f2bf(v);
}

// ------------------------- shared GEMM helpers -----------------------------
// LDS tile: 128 rows x 32 k (ushort). Row's four 16B slices stored XOR-swizzled:
// stored slot p holds logical slice s = p ^ (row & 3).

__device__ __forceinline__ void stage_tile(const unsigned short* __restrict__ ag,
                                           const unsigned short* __restrict__ bg,
                                           int k0, int t,
                                           unsigned short* As, unsigned short* Bs) {
    const int srow = t >> 2;                          // 0..63 within half
    const int scol = ((t & 3) ^ (srow & 3)) * 8;      // swizzled k-slice
#pragma unroll
    for (int i = 0; i < 2; ++i) {
        gload16(ag + (size_t)(i * 64 + srow) * FEAT + k0 + scol,
                (char*)As + i * 4096 + t * 16);
        gload16(bg + (size_t)(i * 64 + srow) * FEAT + k0 + scol,
                (char*)Bs + i * 4096 + t * 16);
    }
}

// fragment read: logical slice s = kstep*2 + half, stored at p = s ^ (row&3)
__device__ __forceinline__ short8 frag(const unsigned short* S, int row, int kstep, int half) {
    const int p = ((kstep * 2 + half) ^ (row & 3));
    return *(const short8*)&S[row * 32 + p * 8];
}

// ----------------------------- routing GEMM --------------------------------
// logits[8192][128] = x_bf16 @ Rt^T ; 64 blocks, 128x128 tile, 32x32x16 MFMA.
__global__ __launch_bounds__(256) void routing_gemm(
        const unsigned short* __restrict__ xb,
        const unsigned short* __restrict__ rt,
        float* __restrict__ logits) {
    __shared__ __align__(16) unsigned short As[128 * 32];
    __shared__ __align__(16) unsigned short Bs[128 * 32];
    const int t    = threadIdx.x;
    const int row0 = blockIdx.x * 128;
    const int wv = t >> 6, ln = t & 63;
    const int wm = wv >> 1, wn = wv & 1;
    const int c32 = ln & 31, half = ln >> 5;

    f32x16 acc[2][2];
#pragma unroll
    for (int i = 0; i < 2; ++i)
#pragma unroll
        for (int j = 0; j < 2; ++j) acc[i][j] = (f32x16)0.0f;

    const unsigned short* ag = xb + (size_t)row0 * FEAT;

    stage_tile(ag, rt, 0, t, As, Bs);
    for (int kk = 0; kk < FEAT / 32; ++kk) {
        __syncthreads();
        short8 a[2][2], b[2][2];
#pragma unroll
        for (int mi = 0; mi < 2; ++mi)
#pragma unroll
            for (int ks = 0; ks < 2; ++ks)
                a[mi][ks] = frag(As, wm * 64 + mi * 32 + c32, ks, half);
#pragma unroll
        for (int ni = 0; ni < 2; ++ni)
#pragma unroll
            for (int ks = 0; ks < 2; ++ks)
                b[ni][ks] = frag(Bs, wn * 64 + ni * 32 + c32, ks, half);
        __syncthreads();
        if (kk + 1 < FEAT / 32) stage_tile(ag, rt, (kk + 1) * 32, t, As, Bs);
#pragma unroll
        for (int mi = 0; mi < 2; ++mi)
#pragma unroll
            for (int ni = 0; ni < 2; ++ni)
#pragma unroll
                for (int ks = 0; ks < 2; ++ks)
                    acc[mi][ni] = __builtin_amdgcn_mfma_f32_32x32x16_bf16(
                        a[mi][ks], b[ni][ks], acc[mi][ni], 0, 0, 0);
    }
#pragma unroll
    for (int mi = 0; mi < 2; ++mi)
#pragma unroll
        for (int ni = 0; ni < 2; ++ni) {
            const int c = wn * 64 + ni * 32 + c32;
#pragma unroll
            for (int reg = 0; reg < 16; ++reg) {
                const int r = wm * 64 + mi * 32 + (reg & 3) + 8 * (reg >> 2) + 4 * half;
                logits[(size_t)(row0 + r) * 128 + c] = acc[mi][ni][reg];
            }
        }
}

// ------------------------------ main GEMM ----------------------------------
// out[b][l*128+c] = lp[b][l] * (sum_k x[b][k]*Wt[l][c][k] + bias[l][c])
// grid = (64 mtiles, 64 leaves); leaf-prob computed in-prologue from logits.
__global__ __launch_bounds__(256) void leaf_gemm(
        const unsigned short* __restrict__ xb,   // [8192][1024] bf16
        const unsigned short* __restrict__ wt,   // [64][128][1024] bf16
        const float* __restrict__ logits,        // [8192][128]
        const float* __restrict__ bias,          // [64][128]
        const int* __restrict__ pn,              // [64][6]
        const int* __restrict__ pd,              // [64][6]
        float* __restrict__ out) {               // [8192][8192]
    __shared__ __align__(16) unsigned short As[128 * 32];
    __shared__ __align__(16) unsigned short Bs[128 * 32];
    __shared__ float lps[128];
    __shared__ float bs[128];

    const int t    = threadIdx.x;
    const int row0 = blockIdx.x * 128;       // batch tile
    const int l    = blockIdx.y;             // leaf = column tile

    const unsigned short* ag = xb + (size_t)row0 * FEAT;
    const unsigned short* bg = wt + (size_t)l * (LEAFD * FEAT);

    // issue first staging BEFORE the leaf-prob loads so both overlap
    stage_tile(ag, bg, 0, t, As, Bs);

    if (t < 128) {
        bs[t] = bias[l * LEAFD + t];
        const int b = row0 + t;
        float prod = 1.0f;
#pragma unroll
        for (int d = 0; d < 6; ++d) {
            const int n   = pn[l * 6 + d];
            const int dir = pd[l * 6 + d];
            if (n >= 0) {
                const float z0 = logits[(size_t)b * 128 + n * 2];
                const float z1 = logits[(size_t)b * 128 + n * 2 + 1];
                const float delta = dir ? (z1 - z0) : (z0 - z1);
                prod *= 1.0f / (1.0f + __expf(-delta));
            }
        }
        lps[t] = prod;
    }

    const int wv = t >> 6, ln = t & 63;
    const int wm = wv >> 1, wn = wv & 1;
    const int c32 = ln & 31, half = ln >> 5;

    f32x16 acc[2][2];
#pragma unroll
    for (int i = 0; i < 2; ++i)
#pragma unroll
        for (int j = 0; j < 2; ++j) acc[i][j] = (f32x16)0.0f;

    for (int kk = 0; kk < FEAT / 32; ++kk) {
        __syncthreads();
        short8 a[2][2], b[2][2];
#pragma unroll
        for (int mi = 0; mi < 2; ++mi)
#pragma unroll
            for (int ks = 0; ks < 2; ++ks)
                a[mi][ks] = frag(As, wm * 64 + mi * 32 + c32, ks, half);
#pragma unroll
        for (int ni = 0; ni < 2; ++ni)
#pragma unroll
            for (int ks = 0; ks < 2; ++ks)
                b[ni][ks] = frag(Bs, wn * 64 + ni * 32 + c32, ks, half);
        __syncthreads();
        if (kk + 1 < FEAT / 32) stage_tile(ag, bg, (kk + 1) * 32, t, As, Bs);
#pragma unroll
        for (int mi = 0; mi < 2; ++mi)
#pragma unroll
            for (int ni = 0; ni < 2; ++ni)
#pragma unroll
                for (int ks = 0; ks < 2; ++ks)
                    acc[mi][ni] = __builtin_amdgcn_mfma_f32_32x32x16_bf16(
                        a[mi][ks], b[ni][ks], acc[mi][ni], 0, 0, 0);
    }

    // epilogue: (acc + bias) * leaf_prob
#pragma unroll
    for (int mi = 0; mi < 2; ++mi)
#pragma unroll
        for (int ni = 0; ni < 2; ++ni) {
            const int c  = wn * 64 + ni * 32 + c32;
            const float bv = bs[c];
#pragma unroll
            for (int reg = 0; reg < 16; ++reg) {
                const int r = wm * 64 + mi * 32 + (reg & 3) + 8 * (reg >> 2) + 4 * half;
                const float v = (acc[mi][ni][reg] + bv) * lps[r];
                out[(size_t)(row0 + r) * OUTD + l * LEAFD + c] = v;
            }
        }
}

// ------------------------------- launcher ----------------------------------

extern "C" void kernel_launch(void* const* d_in, const int* in_sizes, int n_in,
                              void* d_out, int out_size, void* d_ws, size_t ws_size,
                              hipStream_t stream) {
    const float* x    = (const float*)d_in[0];   // [8192][1024]
    const float* rw   = (const float*)d_in[1];   // [63][1024][2]
    const float* lw   = (const float*)d_in[2];   // [64][1024][128]
    const float* bias = (const float*)d_in[3];   // [64][128]
    const int*   pn   = (const int*)d_in[4];     // [64][6]
    const int*   pd   = (const int*)d_in[5];     // [64][6]
    float* out = (float*)d_out;

    char* ws = (char*)d_ws;
    unsigned short* xb     = (unsigned short*)(ws);               // 16 MB
    unsigned short* wt     = (unsigned short*)(ws + 16777216);    // 16 MB
    unsigned short* rt     = (unsigned short*)(ws + 33554432);    // 256 KB
    float*          logits = (float*)(ws + 33816576);             // 4 MB

    cvt_x<<<8192, 256, 0, stream>>>(x, xb);
    cvt_lw<<<dim3(64, 16, 4), 256, 0, stream>>>(lw, wt);
    cvt_rw<<<512, 256, 0, stream>>>(rw, rt);
    routing_gemm<<<64, 256, 0, stream>>>(xb, rt, logits);
    leaf_gemm<<<dim3(64, 64), 256, 0, stream>>>(xb, wt, logits, bias, pn, pd, out);
}